// Round 7
// baseline (435.362 us; speedup 1.0000x reference)
//
#include <hip/hip_runtime.h>

typedef unsigned short u16;
typedef unsigned int   u32;

using bf16x8 = __attribute__((ext_vector_type(8))) __bf16;
using f32x4  = __attribute__((ext_vector_type(4))) float;

__device__ __forceinline__ float bf2f(u16 h){ return __uint_as_float(((u32)h) << 16); }
__device__ __forceinline__ u16 f2bf(float f){
    u32 u = __float_as_uint(f);
    u32 r = u + 0x7FFFu + ((u >> 16) & 1u);   // round-to-nearest-even
    return (u16)(r >> 16);
}

// async global->LDS, 16B per lane; LDS dest = wave-uniform base + lane*16.
__device__ __forceinline__ void async16(const void* g, void* l){
    __builtin_amdgcn_global_load_lds(
        (const __attribute__((address_space(1))) unsigned int*)g,
        (__attribute__((address_space(3))) unsigned int*)l, 16, 0, 0);
}
__device__ __forceinline__ bf16x8 cvt8(uint4 v){
    union { uint4 u; bf16x8 b; } c; c.u = v; return c.b;
}

// ---------------------------------------------------------------------------
// Block 0: dtype probe. flags[0]=1 if floats bf16; flags[1]=mask dtype
// 0=u8,1=i32,2=bf16,3=f32.
// Block 1: label grouping: slot_of_node[n] = label*128+rank (<128) else
// 384+ovf_rank; node_of_slot inverse (-1 = empty); ovf_flag = #overflow.
// Blocks >= 2: grid-stride float4 zero of the sums|sumsOvf|counts region
// (replaces a separate hipMemsetAsync dispatch).
// ---------------------------------------------------------------------------
__global__ void probe_and_perm(const void* x, const void* masks, int* flags,
                               const int* labels, int* slot_of_node,
                               int* node_of_slot, int* ovf_flag,
                               float* zbuf, unsigned int zf4)
{
    if (blockIdx.x >= 2){
        const unsigned int nthr = (gridDim.x - 2) * blockDim.x;
        unsigned int i = (blockIdx.x - 2) * blockDim.x + threadIdx.x;
        float4 z = make_float4(0.f, 0.f, 0.f, 0.f);
        for (; i < zf4; i += nthr)
            reinterpret_cast<float4*>(zbuf)[i] = z;
        return;
    }
    if (blockIdx.x == 0){
        int l = threadIdx.x;
        if (l < 64){
            const u16* hx = (const u16*)x;
            int e0 = (hx[l] >> 7) & 0xFF;
            int e1 = (hx[l + 64] >> 7) & 0xFF;
            unsigned long long b0 = __ballot(e0 >= 100 && e0 <= 140);
            unsigned long long b1 = __ballot(e1 >= 100 && e1 <= 140);
            int cnt = __popcll(b0) + __popcll(b1);
            const u32* w  = (const u32*)masks;
            const u16* hm = (const u16*)masks;
            u32 v = w[l];
            unsigned long long i32bad = __ballot(v > 1u);
            unsigned long long f32bad = __ballot(v != 0u && v != 0x3F800000u);
            u16 h0 = hm[l], h1 = hm[l + 64];
            unsigned long long bfbad =
                __ballot((h0 != 0 && h0 != 0x3F80) || (h1 != 0 && h1 != 0x3F80));
            if (l == 0){
                flags[0] = (cnt >= 100) ? 1 : 0;
                int md = 0;
                if (!i32bad) md = 1; else if (!f32bad) md = 3; else if (!bfbad) md = 2;
                flags[1] = md;
            }
        }
        return;
    }
    __shared__ int lab[300];
    __shared__ unsigned char sp[300];
    int t = threadIdx.x;                      // 320 threads
    for (int idx = t; idx < 512; idx += 320) node_of_slot[idx] = -1;
    if (t < 300) lab[t] = labels[t];
    __syncthreads();
    int r = 0;
    if (t < 300){
        int k = lab[t];
        for (int j = 0; j < t; j++) r += (lab[j] == k);
        sp[t] = (r >= 128) ? 1 : 0;
    }
    __syncthreads();
    if (t < 300){
        int slot;
        if (!sp[t]) slot = lab[t] * 128 + r;
        else {
            int so = 0;
            for (int j = 0; j < t; j++) so += sp[j];
            slot = 384 + so;
        }
        slot_of_node[t] = slot;
        node_of_slot[slot] = t;
    }
    if (t == 0){
        int tot = 0;
        for (int j = 0; j < 300; j++) tot += sp[j];
        *ovf_flag = tot;
    }
}

// ---------------------------------------------------------------------------
// One flat-grid prep kernel: feat transpose (x -> [p][c]), B1T (W1 -> [m][c]),
// W2T (W2 -> [k][r][q]), and bias packing. All bf16-convert, zero-pad j >= J.
// ---------------------------------------------------------------------------
__global__ void prep_combo(const void* x,
    const void* w10, const void* w11, const void* w12,
    const void* w20, const void* w21, const void* w22,
    const void* bb10, const void* bb11, const void* bb12,
    const void* bb20, const void* bb21, const void* bb22,
    u16* feat, u16* B1T, u16* W2T, float* b1f, float* b2f, const int* flags)
{
    __shared__ float tile[32][33];
    const int id = blockIdx.x;
    const bool isbf = (flags[0] != 0);
    const int tid = threadIdx.x;
    const int tx = tid & 31, ty = tid >> 5;

    const void* src; u16* d; int I, J, ldd, i0, j0;
    if (id < 10016){
        int fx = id % 1252, fy = id / 1252;
        src = x; d = feat; I = 256; J = 40000; ldd = 256;
        j0 = fx * 32; i0 = fy * 32;
    } else if (id < 10016 + 768){
        int idx = id - 10016;
        int z = idx / 256, r2 = idx % 256;
        src = (z == 0) ? w10 : (z == 1) ? w11 : w12;
        d = B1T + (size_t)z * 1024 * 256;
        I = 256; J = 1024; ldd = 256;
        j0 = (r2 % 32) * 32; i0 = (r2 / 32) * 32;
    } else if (id < 10016 + 768 + 3072){
        int idx = id - 10016 - 768;
        int z = idx / 1024, r2 = idx % 1024;
        src = (z == 0) ? w20 : (z == 1) ? w21 : w22;
        d = W2T + (size_t)z * 1024 * 1024;
        I = 1024; J = 1024; ldd = 1024;
        j0 = (r2 % 32) * 32; i0 = (r2 / 32) * 32;
    } else {
        int idx = (id - 10016 - 768 - 3072) * 256 + tid;
        if (idx < 3072){
            int k = idx >> 10, r2 = idx & 1023;
            const void* p1 = (k == 0) ? bb10 : (k == 1) ? bb11 : bb12;
            const void* p2 = (k == 0) ? bb20 : (k == 1) ? bb21 : bb22;
            b1f[idx] = isbf ? bf2f(((const u16*)p1)[r2]) : ((const float*)p1)[r2];
            b2f[idx] = isbf ? bf2f(((const u16*)p2)[r2]) : ((const float*)p2)[r2];
        }
        return;
    }
    #pragma unroll
    for (int s = 0; s < 32; s += 8){
        int i = i0 + ty + s, j = j0 + tx;
        float v = 0.f;
        if (j < J){
            size_t ix = (size_t)i * J + j;
            v = isbf ? bf2f(((const u16*)src)[ix]) : ((const float*)src)[ix];
        }
        tile[ty + s][tx] = v;
    }
    __syncthreads();
    #pragma unroll
    for (int s = 0; s < 32; s += 8){
        int j = j0 + ty + s, i = i0 + tx;
        d[(size_t)j * ldd + i] = f2bf(tile[tx][ty + s]);
    }
}

// ---------------------------------------------------------------------------
// masks [P][NN] -> mfT[slot][p] bf16 {0,1} (rows permuted), fused popcount.
// NOTE: mfT is NOT pre-zeroed. All slots with a node get their FULL padded
// row written here (incl. zero pad for p>=40000). Empty-slot rows stay
// garbage: their acc2/sums rows are discarded in l2_gemm (node==-1 gate),
// and MFMA output rows are row-local (D[i][*] depends only on A[i][*]), so
// garbage never contaminates valid rows.
// ---------------------------------------------------------------------------
__global__ void trans_mask_count(const void* src, u16* dst,
                                 const int* slot_of_node, float* counts,
                                 const int* flags)
{
    constexpr int NN_ = 300, P_ = 40000, LDP = 40064;
    __shared__ u16 tile[128][33];    // [p_in][n_in]
    __shared__ int slt[32];
    const int p0 = blockIdx.x * 128, n0 = blockIdx.y * 32;
    const int tid = threadIdx.x;
    const int md = flags[1];
    if (tid < 32) slt[tid] = (n0 + tid < NN_) ? slot_of_node[n0 + tid] : -1;

    if (md == 0){
        const unsigned char* s8 = (const unsigned char*)src;
        const int tx = tid & 7, ty = tid >> 3;
        #pragma unroll
        for (int rep = 0; rep < 4; rep++){
            const int p = p0 + rep * 32 + ty;
            const int nb = n0 + tx * 4;
            u32 w = 0;
            if (p < P_){
                if (nb + 3 < NN_)
                    w = *(const u32*)(s8 + (size_t)p * NN_ + nb);
                else {
                    for (int b = 0; b < 4; b++)
                        if (nb + b < NN_)
                            w |= (u32)s8[(size_t)p * NN_ + nb + b] << (8 * b);
                }
            }
            #pragma unroll
            for (int b = 0; b < 4; b++)
                tile[rep * 32 + ty][tx * 4 + b] =
                    ((w >> (8 * b)) & 0xFFu) ? (u16)0x3F80 : (u16)0;
        }
    } else {
        #pragma unroll
        for (int it = 0; it < 16; it++){
            const int e = tid + it * 256;
            const int n_in = e & 31, p_in = e >> 5;
            const int p = p0 + p_in, n = n0 + n_in;
            u16 v = 0;
            if (p < P_ && n < NN_){
                size_t idx = (size_t)p * NN_ + n;
                bool on;
                if (md == 1)      on = ((const int*)src)[idx] != 0;
                else if (md == 2) on = ((const u16*)src)[idx] != 0;
                else              on = ((const float*)src)[idx] != 0.f;
                v = on ? (u16)0x3F80 : (u16)0;
            }
            tile[p_in][n_in] = v;
        }
    }
    __syncthreads();

    #pragma unroll
    for (int half = 0; half < 2; half++){
        const int row = tid >> 3;
        const int pos = (tid & 7) + half * 8;
        const int slot = slt[row];
        if (slot >= 0){
            union { u16 h[8]; uint4 v; } tmp;
            #pragma unroll
            for (int j = 0; j < 8; j++) tmp.h[j] = tile[pos * 8 + j][row];
            *reinterpret_cast<uint4*>(&dst[(size_t)slot * LDP + p0 + pos * 8]) = tmp.v;
        }
    }
    if (tid < 32){
        const int slot = slt[tid];
        if (slot >= 0){
            int c = 0;
            for (int p = 0; p < 128; p++) c += (tile[p][tid] != 0);
            if (c > 0) atomicAdd(&counts[slot], (float)c);
        }
    }
}

// ---------------------------------------------------------------------------
// FUSED L1 + mask-sum v13: v12 geometry, 8-wave (512-thread) blocks.
// Model (v8/v10/v12): MFMA-busy pinned ~40 us, VALU ~25 us; the rest is
// pipe idle during barrier-synced phases at only 2 waves/SIMD (128 VGPR +
// 128 AGPR per wave). v13 halves per-wave state so 4 waves/SIMD fit:
//  - wave w owns pixels [w*16,w*16+16) in stage-1 and slots [w*16,w*16+16)
//    in stage-2 -> acc1[8] + acc2[8] = 64 AGPR; lean VGPR set (no register
//    prefetch pipeline, masks loaded just-in-time) -> target <= 128 unified.
//  - same 128-m tile, same 80 KB LDS (As 64K + Hs 16K), same global traffic,
//    same total MFMA count; 2 blocks x 8 waves = 16 waves/CU = 4/SIMD.
//  - Hs layout [64 m-half][128 p] bf16 with XOR chunk swizzle
//    (pin>>3)^(m&7): both HWRITE and S2 reads sit at the 32-bank floor.
//  - latency hiding is TLP (4 waves/SIMD), not software pipelining (v11
//    proved reg-prefetch adds nothing here).
// MAP 0: v12's 512-id grid, branch-per-XCD swizzle. MAP 1: overflow.
// ---------------------------------------------------------------------------
template<int MAP>
__global__ __launch_bounds__(512, 4)
void fused_l1_mask(const u16* __restrict__ B1T, const u16* __restrict__ feat,
                   const u16* __restrict__ mfT, const float* __restrict__ b1f,
                   float* __restrict__ sums, const int* __restrict__ skipf)
{
    if constexpr (MAP == 1){ if (*skipf == 0) return; }
    constexpr int PPAD = 40064;
    __shared__ __align__(16) u16 As[32768];   // [8 kt][128 m][32 c]  64 KB
    __shared__ __align__(16) u16 Hs[8192];    // [64 mh][128 p] swz   16 KB

    int bx, ts, te;
    if constexpr (MAP == 0){
        // id = 64g + 8s + r; combo = 8g + r = branch*21 + y; the 8
        // m-subtiles of a (branch, y) share id%8 -> one XCD.
        const int id = blockIdx.x;            // 512 ids, 8 idle
        const int r = id & 7, s = (id >> 3) & 7, g = id >> 6;
        const int combo = g * 8 + r;
        if (combo >= 63) return;
        const int branch = combo / 21, y = combo % 21;
        bx = branch * 8 + s;
        ts = y * 15; te = ts + 15; if (te > 313) te = 313;
    } else {
        bx = blockIdx.x;                      // [0,24) -> m over all 3072
        ts = blockIdx.y * 40; te = ts + 40; if (te > 313) te = 313;
        if (ts >= te) return;
    }
    const int m0 = bx * 128;
    const int srow = (MAP == 0) ? ((bx >> 3) * 128) : 384;

    const int tid = threadIdx.x;              // 512 threads = 8 waves
    const int wave = tid >> 6, lane = tid & 63;
    const int t = lane & 15, q = lane >> 4;

    // stage B1T panel into As once: wave w stages rows [w*16, w*16+16)
    // of the 128-row chunk for every kt (64 lanes x 16B = 1 KB per kt).
    {
        const u16* gA = B1T + (size_t)(m0 + wave * 16 + (lane >> 2)) * 256
                        + (lane & 3) * 8;
        #pragma unroll
        for (int kt = 0; kt < 8; kt++)
            async16(gA + kt * 32, &As[kt * 4096 + wave * 512]);
    }

    // per-wave disjoint global base pointers (q-offset folded in)
    const u16* mrow = mfT + (size_t)(srow + wave * 16 + t) * PPAD + q * 8;
    const u16* gF   = feat + (size_t)(wave * 16 + t) * 256 + q * 8;
    const float4* bsrc = reinterpret_cast<const float4*>(b1f + m0) + q;

    f32x4 acc2[8];
    #pragma unroll
    for (int b = 0; b < 8; b++)
        #pragma unroll
        for (int e = 0; e < 4; e++) acc2[b][e] = 0.f;

    __syncthreads();   // As resident

// all-wave Hs write for m-half HALF: global m = HALF*64 + (mi*16+q*4+i),
// buffer row m_l = mi*16+q*4+i, pixel pin = wave*16+t. XOR chunk swizzle.
#define HWRITE(HALF) do{                                                      \
    const int pin_ = wave * 16 + t;                                           \
    _Pragma("unroll")                                                         \
    for (int mi = 0; mi < 4; mi++){                                           \
        _Pragma("unroll")                                                     \
        for (int i = 0; i < 4; i++){                                          \
            const int m_l = mi * 16 + q * 4 + i;                              \
            float v = acc1[(HALF) * 4 + mi][i];                               \
            v = (v > 0.f) ? v : 0.f;                                          \
            const int cg = (pin_ >> 3) ^ (m_l & 7);                           \
            Hs[m_l * 128 + cg * 8 + (pin_ & 7)] = f2bf(v);                    \
        }                                                                     \
    }                                                                         \
}while(0)

// stage-2 over the resident 64-m half into acc2[NOFF..NOFF+3]; mask frags
// loaded just-in-time (L2-resident, latency hidden by 4-wave/SIMD TLP).
#define S2HALF(NOFF) do{                                                      \
    _Pragma("unroll")                                                         \
    for (int lc = 0; lc < 4; lc++){                                           \
        const uint4 mv = *reinterpret_cast<const uint4*>(mr + lc * 32);       \
        __builtin_amdgcn_s_setprio(1);                                        \
        _Pragma("unroll")                                                     \
        for (int ni = 0; ni < 4; ni++){                                       \
            const int m_ = ni * 16 + t;                                       \
            const int cg = (lc * 4 + q) ^ (m_ & 7);                           \
            bf16x8 hb = *reinterpret_cast<const bf16x8*>(                     \
                &Hs[m_ * 128 + cg * 8]);                                      \
            acc2[(NOFF) + ni] = __builtin_amdgcn_mfma_f32_16x16x32_bf16(      \
                cvt8(mv), hb, acc2[(NOFF) + ni], 0, 0, 0);                    \
        }                                                                     \
        __builtin_amdgcn_s_setprio(0);                                        \
    }                                                                         \
}while(0)

    for (int pt = ts; pt < te; ++pt){
        const int p0 = pt * 128;
        const u16* fF = gF + (size_t)p0 * 256;
        const u16* mr = mrow + p0;

        // acc1 init = bias (b1f is 12 KB, L1-resident)
        f32x4 acc1[8];
        #pragma unroll
        for (int mi = 0; mi < 8; mi++){
            float4 bb = bsrc[mi * 4];
            acc1[mi][0] = bb.x; acc1[mi][1] = bb.y;
            acc1[mi][2] = bb.z; acc1[mi][3] = bb.w;
        }

        // ---- stage-1 K-loop: NO barriers, disjoint feat per wave ----
        #pragma unroll
        for (int kt = 0; kt < 8; ++kt){
            const uint4 fv = *reinterpret_cast<const uint4*>(fF + kt * 32);
            __builtin_amdgcn_s_setprio(1);
            #pragma unroll
            for (int mi = 0; mi < 8; mi++){
                bf16x8 af = *reinterpret_cast<const bf16x8*>(
                    &As[kt * 4096 + (mi * 16 + t) * 32 + q * 8]);
                acc1[mi] = __builtin_amdgcn_mfma_f32_16x16x32_bf16(
                    af, cvt8(fv), acc1[mi], 0, 0, 0);
            }
            __builtin_amdgcn_s_setprio(0);
        }

        // ---- m-half 0 ----
        HWRITE(0);
        __syncthreads();   // Hs half-0 ready
        S2HALF(0);
        __syncthreads();   // protect Hs before half-1 writes

        // ---- m-half 1 ----
        HWRITE(1);
        __syncthreads();   // Hs half-1 ready
        S2HALF(4);
        __syncthreads();   // protect Hs before next p-tile's writes
    }
#undef HWRITE
#undef S2HALF

    // dump accumulators (rows = slots, cols = m)
    #pragma unroll
    for (int i = 0; i < 4; i++){
        const int slot_l = wave * 16 + q * 4 + i;
        #pragma unroll
        for (int ni = 0; ni < 8; ni++){
            const int m_l = ni * 16 + t;
            const float v = acc2[ni][i];
            if constexpr (MAP == 0)
                atomicAdd(sums + (size_t)((bx >> 3) * 128 + slot_l) * 1024
                               + (bx & 7) * 128 + m_l, v);
            else
                atomicAdd(sums + (size_t)slot_l * 3072 + bx * 128 + m_l, v);
        }
    }
}

// ---------------------------------------------------------------------------
// L2 GEMM v2, fully fused, double-buffered: A = sums (fp32) scaled by
// 1/count and bf16-converted during LDS staging; B = W2T via async16.
// Prefetch-depth-1 + ONE barrier per K-step. Epilogue adds bias and
// scatters to d_out via node_of_slot.
// ---------------------------------------------------------------------------
__global__ __launch_bounds__(256)
void l2_gemm(const float* __restrict__ sums3, const float* __restrict__ sumsOvf,
             const float* __restrict__ counts, const u16* __restrict__ W2T,
             const float* __restrict__ b2f, const int* __restrict__ node_of_slot,
             const int* __restrict__ labels, const int* __restrict__ ovfflag,
             void* __restrict__ dout, const int* __restrict__ flags)
{
    const int z = blockIdx.z;
    const int k = (z >= 3) ? z - 3 : z;
    if (z >= 3 && *ovfflag == 0) return;
    const int n0 = blockIdx.x * 128;

    const float* Arow; int astride, slotbase;
    if (z < 3){ Arow = sums3 + (size_t)z * 128 * 1024; astride = 1024; slotbase = z * 128; }
    else      { Arow = sumsOvf + (size_t)k * 1024;     astride = 3072; slotbase = 384; }

    __shared__ __align__(16) u16 As[2][4096];
    __shared__ __align__(16) u16 Bs[2][4096];
    __shared__ float invc[128];

    const int tid  = threadIdx.x;
    const int wave = tid >> 6, lane = tid & 63;
    const int wr = wave >> 1, wc = wave & 1;
    const int t = lane & 15, q = lane >> 4;

    if (tid < 128){
        float c = counts[slotbase + tid];
        invc[tid] = (c > 0.f) ? 1.f / c : 0.f;
    }
    __syncthreads();

    const u16* Bsrc = W2T + (size_t)k * 1024 * 1024;
    const int cr = lane >> 2, cp = lane & 3;
    const int ca = wave * 2, cb = wave * 2 + 1;
    const u16* gB0 = Bsrc + (size_t)(n0 + ca * 16 + cr) * 1024 + cp * 8;
    const u16* gB1 = Bsrc + (size_t)(n0 + cb * 16 + cr) * 1024 + cp * 8;

    const int srow0 = tid >> 2, sq0 = tid & 3;     // A-staging row/quarter
    const int srow1 = srow0 + 64;

    float4 sv[2][2];

#define L2_LOAD(ktv) do{ \
    const float4* _p0 = reinterpret_cast<const float4*>( \
        Arow + (size_t)srow0 * astride + (ktv) * 32 + sq0 * 8); \
    const float4* _p1 = reinterpret_cast<const float4*>( \
        Arow + (size_t)srow1 * astride + (ktv) * 32 + sq0 * 8); \
    sv[0][0] = _p0[0]; sv[0][1] = _p0[1]; \
    sv[1][0] = _p1[0]; sv[1][1] = _p1[1]; }while(0)

#define L2_WRITE(bufv) do{ \
    _Pragma("unroll") \
    for (int rep = 0; rep < 2; rep++){ \
        const int row = (rep == 0) ? srow0 : srow1; \
        const float s = invc[row]; \
        float4 v0 = sv[rep][0], v1 = sv[rep][1]; \
        union { u16 h[8]; uint4 v; } pk; \
        pk.h[0] = f2bf(v0.x * s); pk.h[1] = f2bf(v0.y * s); \
        pk.h[2] = f2bf(v0.z * s); pk.h[3] = f2bf(v0.w * s); \
        pk.h[4] = f2bf(v1.x * s); pk.h[5] = f2bf(v1.y * s); \
        pk.h[6] = f2bf(v1.z * s); pk.h[7] = f2bf(v1.w * s); \
        *reinterpret_cast<uint4*>(&As[bufv][row * 32 + sq0 * 8]) = pk.v; \
    } }while(0)

    // prologue: stage kt=0 into buffer 0
    L2_LOAD(0);
    L2_WRITE(0);
    async16(gB0, &Bs[0][ca * 512]);
    async16(gB1, &Bs[0][cb * 512]);
    __syncthreads();

    f32x4 acc[4][4];
    #pragma unroll
    for (int a = 0; a < 4; a++)
        #pragma unroll
        for (int b = 0; b < 4; b++)
            #pragma unroll
            for (int e = 0; e < 4; e++) acc[a][b][e] = 0.f;

    int buf = 0;
    for (int kt = 0; kt < 32; ++kt){
        if (kt < 31) L2_LOAD(kt + 1);                     // global A, kt+1
        bf16x8 af[4], bg[4];
        #pragma unroll
        for (int mi = 0; mi < 4; mi++)
            af[mi] = *reinterpret_cast<const bf16x8*>(
                &As[buf][(wr * 64 + mi * 16 + t) * 32 + q * 8]);
        #pragma unroll
        for (int ni = 0; ni < 4; ni++)
            bg[ni] = *reinterpret_cast<const bf16x8*>(
                &Bs[buf][(wc * 64 + ni * 16 + t) * 32 + q * 8]);
        if (kt < 31){
            async16(gB0 + (kt + 1) * 32, &Bs[buf ^ 1][ca * 512]);
            async16(gB1 + (kt + 1) * 32, &Bs[buf ^ 1][cb * 512]);
        }
        __builtin_amdgcn_s_setprio(1);
        #pragma unroll
        for (int mi = 0; mi < 4; mi++)
            #pragma unroll
            for (int ni = 0; ni < 4; ni++)
                acc[mi][ni] = __builtin_amdgcn_mfma_f32_16x16x32_bf16(
                    af[mi], bg[ni], acc[mi][ni], 0, 0, 0);
        __builtin_amdgcn_s_setprio(0);
        if (kt < 31) L2_WRITE(buf ^ 1);                   // LDS A, kt+1
        __syncthreads();
        buf ^= 1;
    }
#undef L2_LOAD
#undef L2_WRITE

    const bool outbf = (flags[0] != 0);
    #pragma unroll
    for (int mi = 0; mi < 4; mi++){
        #pragma unroll
        for (int i = 0; i < 4; i++){
            int m_l = wr * 64 + mi * 16 + q * 4 + i;
            int node = node_of_slot[slotbase + m_l];
            bool ok = (node >= 0) && (z < 3 || labels[node] == k);
            if (!ok) continue;
            #pragma unroll
            for (int ni = 0; ni < 4; ni++){
                int n = n0 + wc * 64 + ni * 16 + t;
                float v = acc[mi][ni][i] + b2f[k * 1024 + n];
                size_t oi = (size_t)node * 1024 + n;
                if (outbf) ((u16*)dout)[oi] = f2bf(v);
                else       ((float*)dout)[oi] = v;
            }
        }
    }
}

// ---------------------------------------------------------------------------
extern "C" void kernel_launch(void* const* d_in, const int* in_sizes, int n_in,
                              void* d_out, int out_size, void* d_ws, size_t ws_size,
                              hipStream_t stream)
{
    constexpr int C = 256, R = 1024;
    constexpr int PPAD = 40064;          // 313 * 128
    constexpr int M1 = 3 * R;            // 3072 L1 rows (branch-major)
    constexpr int SLOTS = 512;           // 3*128 grouped + 128 overflow

    const void* x      = d_in[0];
    const void* masks  = d_in[1];
    const int*  labels = (const int*)d_in[2];
    (void)in_sizes; (void)n_in; (void)out_size; (void)ws_size;

    char* ws = (char*)d_ws;
    size_t off = 0;
    auto alloc = [&](size_t b)->size_t {
        size_t o = off; off += (b + 255) & ~(size_t)255; return o;
    };

    int*   flags   = (int*)  (ws + alloc(256));
    int*   slotmap = (int*)  (ws + alloc(384 * 4));
    int*   nodemap = (int*)  (ws + alloc(512 * 4));
    int*   ovfflag = (int*)  (ws + alloc(256));
    u16*   feat    = (u16*)  (ws + alloc((size_t)PPAD * C * 2));    // [p][c]
    u16*   B1T     = (u16*)  (ws + alloc((size_t)M1 * C * 2));      // [m][c]
    float* b1f     = (float*)(ws + alloc((size_t)M1 * 4));
    float* b2f     = (float*)(ws + alloc((size_t)M1 * 4));
    u16*   mfT     = (u16*)  (ws + alloc((size_t)SLOTS * PPAD * 2));// [slot][p]
    // contiguous zero region: sums3 | sumsOvf | counts
    float* sums3   = (float*)(ws + alloc((size_t)384 * 1024 * 4));
    float* sumsOvf = (float*)(ws + alloc((size_t)128 * M1 * 4));
    float* counts  = (float*)(ws + alloc((size_t)SLOTS * 4));
    u16*   W2T     = (u16*)  (ws + alloc((size_t)3 * R * R * 2));

    // sums|sumsOvf|counts zero region, in float4 units (all 256B-aligned,
    // contiguous by construction of alloc()).
    const unsigned int zf4 =
        (384u * 1024u + 128u * 3072u + 512u) / 4u;

    // probe + perm + sums-memset in one launch (blocks >= 2 do the memset)
    probe_and_perm<<<66, 320, 0, stream>>>(x, masks, flags, labels,
                                           slotmap, nodemap, ovfflag,
                                           sums3, zf4);
    // NOTE: mfT memset dropped — empty-slot rows carry garbage by design;
    // their sums rows are never consumed (node_of_slot gate in l2_gemm).

    prep_combo<<<10016 + 768 + 3072 + 12, 256, 0, stream>>>(
        x, d_in[3], d_in[7], d_in[11],           // W1
        d_in[5], d_in[9], d_in[13],              // W2
        d_in[4], d_in[8], d_in[12],              // b1
        d_in[6], d_in[10], d_in[14],             // b2
        feat, B1T, W2T, b1f, b2f, flags);

    trans_mask_count<<<dim3(PPAD / 128, 384 / 32), 256, 0, stream>>>(
        masks, mfT, slotmap, counts, flags);

    // fused L1 + mask-sum: 512 ids (8 idle), branch-per-XCD swizzle,
    // 512-thread / 8-wave blocks (4 waves/SIMD at 80 KB LDS x 2 blocks/CU)
    fused_l1_mask<0><<<512, 512, 0, stream>>>(
        B1T, feat, mfT, b1f, sums3, nullptr);
    // overflow path (skipped unless some label has > 128 nodes)
    fused_l1_mask<1><<<dim3(24, 8), 512, 0, stream>>>(
        B1T, feat, mfT, b1f, sumsOvf, ovfflag);

    // L2 + means + output gather, one launch
    l2_gemm<<<dim3(8, 1, 6), 256, 0, stream>>>(
        sums3, sumsOvf, counts, W2T, b2f, nodemap, labels, ovfflag,
        d_out, flags);
}

// Round 8
// 365.960 us; speedup vs baseline: 1.1896x; 1.1896x over previous
//
#include <hip/hip_runtime.h>

typedef unsigned short u16;
typedef unsigned int   u32;

using bf16x8 = __attribute__((ext_vector_type(8))) __bf16;
using f32x4  = __attribute__((ext_vector_type(4))) float;

__device__ __forceinline__ float bf2f(u16 h){ return __uint_as_float(((u32)h) << 16); }
__device__ __forceinline__ u16 f2bf(float f){
    u32 u = __float_as_uint(f);
    u32 r = u + 0x7FFFu + ((u >> 16) & 1u);   // round-to-nearest-even
    return (u16)(r >> 16);
}

// async global->LDS, 16B per lane; LDS dest = wave-uniform base + lane*16.
__device__ __forceinline__ void async16(const void* g, void* l){
    __builtin_amdgcn_global_load_lds(
        (const __attribute__((address_space(1))) unsigned int*)g,
        (__attribute__((address_space(3))) unsigned int*)l, 16, 0, 0);
}
__device__ __forceinline__ bf16x8 cvt8(uint4 v){
    union { uint4 u; bf16x8 b; } c; c.u = v; return c.b;
}

// ---------------------------------------------------------------------------
// MEGA PREP v14: one launch fusing 4 independent block families (tail was
// ~228 us of SERIALIZED stream ops; prep & trans are independent BW streams
// that now overlap on the machine):
//   id 0            : dtype probe -> flags (consumed only by l2 epilogue)
//   id 1            : label grouping -> node_of_slot, ovf_flag
//   id 2..13857     : prep_combo work (feat/B1T/W2T transpose + bias pack),
//                     isbf derived LOCALLY per block (64-lane ballot)
//   id 13858..17613 : trans_mask_count work (313 x 12 flattened), mask dtype
//                     AND slot mapping derived LOCALLY per block (same
//                     algorithm as grouping block -> identical mapping)
// Disjoint outputs per family -> no intra-kernel races. counts pre-zeroed
// by the memset stream op that precedes this kernel.
// ---------------------------------------------------------------------------
__global__ __launch_bounds__(256)
void mega_prep(const void* x, const void* masks, const int* labels,
    const void* w10, const void* w11, const void* w12,
    const void* w20, const void* w21, const void* w22,
    const void* bb10, const void* bb11, const void* bb12,
    const void* bb20, const void* bb21, const void* bb22,
    u16* feat, u16* B1T, u16* W2T, float* b1f, float* b2f,
    u16* mfT, float* counts,
    int* flags, int* node_of_slot, int* ovf_flag)
{
    constexpr int NN_ = 300, P_ = 40000, LDP = 40064;
    constexpr int PREP_BASE = 2, NPREP = 10016 + 768 + 3072 + 12;
    constexpr int TRANS_BASE = PREP_BASE + NPREP;

    __shared__ float ftile[32][33];       // prep transpose tile
    __shared__ u16 mtile[128][33];        // trans transpose tile
    __shared__ int lab[NN_];
    __shared__ short rnk[NN_];
    __shared__ unsigned char sp[NN_];
    __shared__ int slt[32];
    __shared__ int s_info;                // local isbf / md

    const int id = blockIdx.x;
    const int tid = threadIdx.x;

    // ================= id 0: dtype probe -> flags =================
    if (id == 0){
        if (tid < 64){
            const u16* hx = (const u16*)x;
            int e0 = (hx[tid] >> 7) & 0xFF;
            int e1 = (hx[tid + 64] >> 7) & 0xFF;
            unsigned long long b0 = __ballot(e0 >= 100 && e0 <= 140);
            unsigned long long b1 = __ballot(e1 >= 100 && e1 <= 140);
            int cnt = __popcll(b0) + __popcll(b1);
            const u32* w  = (const u32*)masks;
            const u16* hm = (const u16*)masks;
            u32 v = w[tid];
            unsigned long long i32bad = __ballot(v > 1u);
            unsigned long long f32bad = __ballot(v != 0u && v != 0x3F800000u);
            u16 h0 = hm[tid], h1 = hm[tid + 64];
            unsigned long long bfbad =
                __ballot((h0 != 0 && h0 != 0x3F80) || (h1 != 0 && h1 != 0x3F80));
            if (tid == 0){
                flags[0] = (cnt >= 100) ? 1 : 0;
                int md = 0;
                if (!i32bad) md = 1; else if (!f32bad) md = 3; else if (!bfbad) md = 2;
                flags[1] = md;
            }
        }
        return;
    }

    // ================= id 1: label grouping =================
    if (id == 1){
        for (int idx = tid; idx < 512; idx += 256) node_of_slot[idx] = -1;
        for (int n = tid; n < NN_; n += 256) lab[n] = labels[n];
        __syncthreads();
        for (int n = tid; n < NN_; n += 256){
            int k = lab[n], r = 0;
            for (int j = 0; j < n; j++) r += (lab[j] == k);
            rnk[n] = (short)r; sp[n] = (r >= 128) ? 1 : 0;
        }
        __syncthreads();
        for (int n = tid; n < NN_; n += 256){
            int r = rnk[n]; int slot;
            if (r < 128) slot = lab[n] * 128 + r;
            else { int so = 0; for (int j = 0; j < n; j++) so += sp[j]; slot = 384 + so; }
            node_of_slot[slot] = n;
        }
        if (tid == 0){
            int tot = 0;
            for (int j = 0; j < NN_; j++) tot += sp[j];
            *ovf_flag = tot;
        }
        return;
    }

    // ================= prep family =================
    if (id < TRANS_BASE){
        // local isbf probe (wave 0)
        if (tid < 64){
            const u16* hx = (const u16*)x;
            int e0 = (hx[tid] >> 7) & 0xFF;
            int e1 = (hx[tid + 64] >> 7) & 0xFF;
            unsigned long long b0 = __ballot(e0 >= 100 && e0 <= 140);
            unsigned long long b1 = __ballot(e1 >= 100 && e1 <= 140);
            if (tid == 0) s_info = (__popcll(b0) + __popcll(b1) >= 100) ? 1 : 0;
        }
        __syncthreads();
        const bool isbf = (s_info != 0);
        const int pid = id - PREP_BASE;
        const int tx = tid & 31, ty = tid >> 5;

        const void* src; u16* d; int J, ldd, i0, j0;
        if (pid < 10016){
            int fx = pid % 1252, fy = pid / 1252;
            src = x; d = feat; J = 40000; ldd = 256;
            j0 = fx * 32; i0 = fy * 32;
        } else if (pid < 10016 + 768){
            int idx = pid - 10016;
            int z = idx / 256, r2 = idx % 256;
            src = (z == 0) ? w10 : (z == 1) ? w11 : w12;
            d = B1T + (size_t)z * 1024 * 256;
            J = 1024; ldd = 256;
            j0 = (r2 % 32) * 32; i0 = (r2 / 32) * 32;
        } else if (pid < 10016 + 768 + 3072){
            int idx = pid - 10016 - 768;
            int z = idx / 1024, r2 = idx % 1024;
            src = (z == 0) ? w20 : (z == 1) ? w21 : w22;
            d = W2T + (size_t)z * 1024 * 1024;
            J = 1024; ldd = 1024;
            j0 = (r2 % 32) * 32; i0 = (r2 / 32) * 32;
        } else {
            int idx = (pid - 10016 - 768 - 3072) * 256 + tid;
            if (idx < 3072){
                int k = idx >> 10, r2 = idx & 1023;
                const void* p1 = (k == 0) ? bb10 : (k == 1) ? bb11 : bb12;
                const void* p2 = (k == 0) ? bb20 : (k == 1) ? bb21 : bb22;
                b1f[idx] = isbf ? bf2f(((const u16*)p1)[r2]) : ((const float*)p1)[r2];
                b2f[idx] = isbf ? bf2f(((const u16*)p2)[r2]) : ((const float*)p2)[r2];
            }
            return;
        }
        #pragma unroll
        for (int s = 0; s < 32; s += 8){
            int i = i0 + ty + s, j = j0 + tx;
            float v = 0.f;
            if (j < J){
                size_t ix = (size_t)i * J + j;
                v = isbf ? bf2f(((const u16*)src)[ix]) : ((const float*)src)[ix];
            }
            ftile[ty + s][tx] = v;
        }
        __syncthreads();
        #pragma unroll
        for (int s = 0; s < 32; s += 8){
            int j = j0 + ty + s, i = i0 + tx;
            d[(size_t)j * ldd + i] = f2bf(ftile[tx][ty + s]);
        }
        return;
    }

    // ================= trans family =================
    {
        const int idx = id - TRANS_BASE;          // [0, 3756)
        const int pb = idx % 313, nb = idx / 313; // nb in [0,12)
        const int p0 = pb * 128, n0 = nb * 32;

        // labels + local md probe
        for (int n = tid; n < NN_; n += 256) lab[n] = labels[n];
        if (tid < 64){
            const u32* w  = (const u32*)masks;
            const u16* hm = (const u16*)masks;
            u32 v = w[tid];
            unsigned long long i32bad = __ballot(v > 1u);
            unsigned long long f32bad = __ballot(v != 0u && v != 0x3F800000u);
            u16 h0 = hm[tid], h1 = hm[tid + 64];
            unsigned long long bfbad =
                __ballot((h0 != 0 && h0 != 0x3F80) || (h1 != 0 && h1 != 0x3F80));
            if (tid == 0){
                int md = 0;
                if (!i32bad) md = 1; else if (!f32bad) md = 3; else if (!bfbad) md = 2;
                s_info = md;
            }
        }
        __syncthreads();
        const int md = s_info;

        // local ranks (same algorithm as grouping block -> identical map)
        for (int n = tid; n < NN_; n += 256){
            int k = lab[n], r = 0;
            for (int j = 0; j < n; j++) r += (lab[j] == k);
            rnk[n] = (short)r; sp[n] = (r >= 128) ? 1 : 0;
        }
        __syncthreads();
        if (tid < 32){
            int n = n0 + tid;
            int slot = -1;
            if (n < NN_){
                int r = rnk[n];
                if (r < 128) slot = lab[n] * 128 + r;
                else { int so = 0; for (int j = 0; j < n; j++) so += sp[j]; slot = 384 + so; }
            }
            slt[tid] = slot;
        }

        // tile fill
        if (md == 0){
            const unsigned char* s8 = (const unsigned char*)masks;
            const int tx = tid & 7, ty = tid >> 3;
            #pragma unroll
            for (int rep = 0; rep < 4; rep++){
                const int p = p0 + rep * 32 + ty;
                const int nbyte = n0 + tx * 4;
                u32 w = 0;
                if (p < P_){
                    if (nbyte + 3 < NN_)
                        w = *(const u32*)(s8 + (size_t)p * NN_ + nbyte);
                    else {
                        for (int b = 0; b < 4; b++)
                            if (nbyte + b < NN_)
                                w |= (u32)s8[(size_t)p * NN_ + nbyte + b] << (8 * b);
                    }
                }
                #pragma unroll
                for (int b = 0; b < 4; b++)
                    mtile[rep * 32 + ty][tx * 4 + b] =
                        ((w >> (8 * b)) & 0xFFu) ? (u16)0x3F80 : (u16)0;
            }
        } else {
            #pragma unroll
            for (int it = 0; it < 16; it++){
                const int e = tid + it * 256;
                const int n_in = e & 31, p_in = e >> 5;
                const int p = p0 + p_in, n = n0 + n_in;
                u16 v = 0;
                if (p < P_ && n < NN_){
                    size_t ix = (size_t)p * NN_ + n;
                    bool on;
                    if (md == 1)      on = ((const int*)masks)[ix] != 0;
                    else if (md == 2) on = ((const u16*)masks)[ix] != 0;
                    else              on = ((const float*)masks)[ix] != 0.f;
                    v = on ? (u16)0x3F80 : (u16)0;
                }
                mtile[p_in][n_in] = v;
            }
        }
        __syncthreads();

        #pragma unroll
        for (int half = 0; half < 2; half++){
            const int row = tid >> 3;
            const int pos = (tid & 7) + half * 8;
            const int slot = slt[row];
            if (slot >= 0){
                union { u16 h[8]; uint4 v; } tmp;
                #pragma unroll
                for (int j = 0; j < 8; j++) tmp.h[j] = mtile[pos * 8 + j][row];
                *reinterpret_cast<uint4*>(&mfT[(size_t)slot * LDP + p0 + pos * 8]) = tmp.v;
            }
        }
        if (tid < 32){
            const int slot = slt[tid];
            if (slot >= 0){
                int c = 0;
                for (int p = 0; p < 128; p++) c += (mtile[p][tid] != 0);
                if (c > 0) atomicAdd(&counts[slot], (float)c);
            }
        }
    }
}

// ---------------------------------------------------------------------------
// FUSED L1 + mask-sum v12 (FROZEN — 123 us measured, best of v8..v13):
// 128-m tile, 64 KB As, 2 blocks/CU; Hs split along M ([4 pc][64 mh][32 p]),
// all-wave writes, 4 barriers/pt; masks loaded once at kt=6/7, reused by
// both halves. MFMA-busy is pinned at ~39 us across all structural
// variants; v12 minimizes the barrier-phase idle.
// MAP 0: 512-id grid, branch-per-XCD swizzle. MAP 1: overflow, early-out.
// ---------------------------------------------------------------------------
template<int MAP>
__global__ __launch_bounds__(256, 2)
void fused_l1_mask(const u16* __restrict__ B1T, const u16* __restrict__ feat,
                   const u16* __restrict__ mfT, const float* __restrict__ b1f,
                   float* __restrict__ sums, const int* __restrict__ skipf)
{
    if constexpr (MAP == 1){ if (*skipf == 0) return; }
    constexpr int PPAD = 40064;
    __shared__ __align__(16) u16 As[32768];   // [8 kt][128 m][32 c]  64 KB
    __shared__ __align__(16) u16 Hs[8192];    // [4 pc][64 mh][32 p]  16 KB

    int bx, ts, te;
    if constexpr (MAP == 0){
        const int id = blockIdx.x;            // 512 ids, 8 idle
        const int r = id & 7, s = (id >> 3) & 7, g = id >> 6;
        const int combo = g * 8 + r;
        if (combo >= 63) return;
        const int branch = combo / 21, y = combo % 21;
        bx = branch * 8 + s;
        ts = y * 15; te = ts + 15; if (te > 313) te = 313;
    } else {
        bx = blockIdx.x;                      // [0,24) -> m over all 3072
        ts = blockIdx.y * 40; te = ts + 40; if (te > 313) te = 313;
        if (ts >= te) return;
    }
    const int m0 = bx * 128;
    const int srow = (MAP == 0) ? ((bx >> 3) * 128) : 384;

    const int tid = threadIdx.x;
    const int wave = tid >> 6, lane = tid & 63;
    const int t = lane & 15, q = lane >> 4;

    {
        const int cr = lane >> 2, cp = lane & 3;
        const int ca = wave * 2, cb = wave * 2 + 1;
        const u16* gA0 = B1T + (size_t)(m0 + ca * 16 + cr) * 256 + cp * 8;
        const u16* gA1 = B1T + (size_t)(m0 + cb * 16 + cr) * 256 + cp * 8;
        #pragma unroll
        for (int kt = 0; kt < 8; kt++){
            async16(gA0 + kt * 32, &As[kt * 4096 + ca * 512]);
            async16(gA1 + kt * 32, &As[kt * 4096 + cb * 512]);
        }
    }

    const u16* mrow = mfT + (size_t)(srow + wave * 32 + t) * PPAD + q * 8;
    const u16* gF   = feat + (size_t)(wave * 32 + t) * 256 + q * 8;
    const float4* bsrc = reinterpret_cast<const float4*>(b1f + m0) + q;

    f32x4 acc2[2][8];
    #pragma unroll
    for (int a = 0; a < 2; a++)
        #pragma unroll
        for (int b = 0; b < 8; b++)
            #pragma unroll
            for (int e = 0; e < 4; e++) acc2[a][b][e] = 0.f;

    uint4 bgv[2];
    #pragma unroll
    for (int ni = 0; ni < 2; ni++)
        bgv[ni] = *reinterpret_cast<const uint4*>(
            gF + (size_t)(ts * 128 + ni * 16) * 256);

    __syncthreads();   // As resident (+ bgv drained)

#define HWRITE(MOFF) do{                                                      \
    _Pragma("unroll")                                                         \
    for (int mi = 0; mi < 4; mi++){                                           \
        _Pragma("unroll")                                                     \
        for (int i = 0; i < 4; i++){                                          \
            const int m_l = mi * 16 + q * 4 + i;                              \
            _Pragma("unroll")                                                 \
            for (int ni = 0; ni < 2; ni++){                                   \
                const int pin = ni * 16 + t;                                  \
                float v = acc1[(MOFF) + mi][ni][i];                           \
                v = (v > 0.f) ? v : 0.f;                                      \
                const int cg = (pin >> 3) ^ q;                                \
                Hs[wave * 2048 + m_l * 32 + cg * 8 + (pin & 7)] = f2bf(v);    \
            }                                                                 \
        }                                                                     \
    }                                                                         \
}while(0)

#define S2HALF(NOFF) do{                                                      \
    _Pragma("unroll")                                                         \
    for (int lc = 0; lc < 4; lc++){                                           \
        const int hq_ = (q ^ ((t >> 2) & 3)) * 8;                             \
        bf16x8 hb0_ = *reinterpret_cast<const bf16x8*>(                       \
            &Hs[lc * 2048 + (0 * 16 + t) * 32 + hq_]);                        \
        bf16x8 hb1_ = *reinterpret_cast<const bf16x8*>(                       \
            &Hs[lc * 2048 + (1 * 16 + t) * 32 + hq_]);                        \
        bf16x8 hb2_ = *reinterpret_cast<const bf16x8*>(                       \
            &Hs[lc * 2048 + (2 * 16 + t) * 32 + hq_]);                        \
        bf16x8 hb3_ = *reinterpret_cast<const bf16x8*>(                       \
            &Hs[lc * 2048 + (3 * 16 + t) * 32 + hq_]);                        \
        __builtin_amdgcn_s_setprio(1);                                        \
        acc2[0][(NOFF)+0] = __builtin_amdgcn_mfma_f32_16x16x32_bf16(          \
            cvt8(mk[lc][0]), hb0_, acc2[0][(NOFF)+0], 0, 0, 0);               \
        acc2[0][(NOFF)+1] = __builtin_amdgcn_mfma_f32_16x16x32_bf16(          \
            cvt8(mk[lc][0]), hb1_, acc2[0][(NOFF)+1], 0, 0, 0);               \
        acc2[0][(NOFF)+2] = __builtin_amdgcn_mfma_f32_16x16x32_bf16(          \
            cvt8(mk[lc][0]), hb2_, acc2[0][(NOFF)+2], 0, 0, 0);               \
        acc2[0][(NOFF)+3] = __builtin_amdgcn_mfma_f32_16x16x32_bf16(          \
            cvt8(mk[lc][0]), hb3_, acc2[0][(NOFF)+3], 0, 0, 0);               \
        acc2[1][(NOFF)+0] = __builtin_amdgcn_mfma_f32_16x16x32_bf16(          \
            cvt8(mk[lc][1]), hb0_, acc2[1][(NOFF)+0], 0, 0, 0);               \
        acc2[1][(NOFF)+1] = __builtin_amdgcn_mfma_f32_16x16x32_bf16(          \
            cvt8(mk[lc][1]), hb1_, acc2[1][(NOFF)+1], 0, 0, 0);               \
        acc2[1][(NOFF)+2] = __builtin_amdgcn_mfma_f32_16x16x32_bf16(          \
            cvt8(mk[lc][1]), hb2_, acc2[1][(NOFF)+2], 0, 0, 0);               \
        acc2[1][(NOFF)+3] = __builtin_amdgcn_mfma_f32_16x16x32_bf16(          \
            cvt8(mk[lc][1]), hb3_, acc2[1][(NOFF)+3], 0, 0, 0);               \
        __builtin_amdgcn_s_setprio(0);                                        \
    }                                                                         \
}while(0)

    for (int pt = ts; pt < te; ++pt){
        const int p0 = pt * 128;

        f32x4 acc1[8][2];
        #pragma unroll
        for (int mi = 0; mi < 8; mi++){
            float4 bb = bsrc[mi * 4];
            #pragma unroll
            for (int ni = 0; ni < 2; ni++){
                acc1[mi][ni][0] = bb.x; acc1[mi][ni][1] = bb.y;
                acc1[mi][ni][2] = bb.z; acc1[mi][ni][3] = bb.w;
            }
        }

        uint4 mk[4][2];   // mask frags [lc][si], loaded once, used twice

        #pragma unroll
        for (int kt = 0; kt < 8; ++kt){
            bf16x8 af[8];
            #pragma unroll
            for (int mi = 0; mi < 8; mi++)
                af[mi] = *reinterpret_cast<const bf16x8*>(
                    &As[kt * 4096 + (mi * 16 + t) * 32 + q * 8]);
            uint4 nxt[2];
            if (kt < 7){
                #pragma unroll
                for (int ni = 0; ni < 2; ni++)
                    nxt[ni] = *reinterpret_cast<const uint4*>(
                        gF + (size_t)(p0 + ni * 16) * 256 + (kt + 1) * 32);
            }
            if (kt == 6){
                #pragma unroll
                for (int si = 0; si < 2; si++){
                    mk[0][si] = *reinterpret_cast<const uint4*>(
                        mrow + (size_t)(si * 16) * PPAD + p0 + 0 * 32);
                    mk[1][si] = *reinterpret_cast<const uint4*>(
                        mrow + (size_t)(si * 16) * PPAD + p0 + 1 * 32);
                }
            } else if (kt == 7){
                #pragma unroll
                for (int si = 0; si < 2; si++){
                    mk[2][si] = *reinterpret_cast<const uint4*>(
                        mrow + (size_t)(si * 16) * PPAD + p0 + 2 * 32);
                    mk[3][si] = *reinterpret_cast<const uint4*>(
                        mrow + (size_t)(si * 16) * PPAD + p0 + 3 * 32);
                }
            }
            __builtin_amdgcn_s_setprio(1);
            #pragma unroll
            for (int mi = 0; mi < 8; mi++)
                #pragma unroll
                for (int ni = 0; ni < 2; ni++)
                    acc1[mi][ni] = __builtin_amdgcn_mfma_f32_16x16x32_bf16(
                        af[mi], cvt8(bgv[ni]), acc1[mi][ni], 0, 0, 0);
            __builtin_amdgcn_s_setprio(0);
            if (kt < 7){ bgv[0] = nxt[0]; bgv[1] = nxt[1]; }
        }

        HWRITE(0);
        __syncthreads();   // Hs half-0 ready; mk drained (vmcnt 0)

        S2HALF(0);
        __syncthreads();   // protect Hs before half-1 writes

        HWRITE(4);
        if (pt + 1 < te){
            #pragma unroll
            for (int ni = 0; ni < 2; ni++)
                bgv[ni] = *reinterpret_cast<const uint4*>(
                    gF + (size_t)((pt + 1) * 128 + ni * 16) * 256);
        }
        __syncthreads();   // Hs half-1 ready

        S2HALF(4);
        __syncthreads();   // protect Hs before next p-tile's writes
    }
#undef HWRITE
#undef S2HALF

    #pragma unroll
    for (int si = 0; si < 2; si++){
        #pragma unroll
        for (int i = 0; i < 4; i++){
            const int slot_l = wave * 32 + si * 16 + q * 4 + i;
            #pragma unroll
            for (int ni = 0; ni < 8; ni++){
                const int m_l = ni * 16 + t;
                const float v = acc2[si][ni][i];
                if constexpr (MAP == 0)
                    atomicAdd(sums + (size_t)((bx >> 3) * 128 + slot_l) * 1024
                                   + (bx & 7) * 128 + m_l, v);
                else
                    atomicAdd(sums + (size_t)slot_l * 3072 + bx * 128 + m_l, v);
            }
        }
    }
}

// ---------------------------------------------------------------------------
// L2 GEMM v2, fully fused, double-buffered: A = sums (fp32) scaled by
// 1/count and bf16-converted during LDS staging; B = W2T via async16.
// Prefetch-depth-1 + ONE barrier per K-step. Epilogue adds bias and
// scatters to d_out via node_of_slot.
// ---------------------------------------------------------------------------
__global__ __launch_bounds__(256)
void l2_gemm(const float* __restrict__ sums3, const float* __restrict__ sumsOvf,
             const float* __restrict__ counts, const u16* __restrict__ W2T,
             const float* __restrict__ b2f, const int* __restrict__ node_of_slot,
             const int* __restrict__ labels, const int* __restrict__ ovfflag,
             void* __restrict__ dout, const int* __restrict__ flags)
{
    const int z = blockIdx.z;
    const int k = (z >= 3) ? z - 3 : z;
    if (z >= 3 && *ovfflag == 0) return;
    const int n0 = blockIdx.x * 128;

    const float* Arow; int astride, slotbase;
    if (z < 3){ Arow = sums3 + (size_t)z * 128 * 1024; astride = 1024; slotbase = z * 128; }
    else      { Arow = sumsOvf + (size_t)k * 1024;     astride = 3072; slotbase = 384; }

    __shared__ __align__(16) u16 As[2][4096];
    __shared__ __align__(16) u16 Bs[2][4096];
    __shared__ float invc[128];

    const int tid  = threadIdx.x;
    const int wave = tid >> 6, lane = tid & 63;
    const int wr = wave >> 1, wc = wave & 1;
    const int t = lane & 15, q = lane >> 4;

    if (tid < 128){
        float c = counts[slotbase + tid];
        invc[tid] = (c > 0.f) ? 1.f / c : 0.f;
    }
    __syncthreads();

    const u16* Bsrc = W2T + (size_t)k * 1024 * 1024;
    const int cr = lane >> 2, cp = lane & 3;
    const int ca = wave * 2, cb = wave * 2 + 1;
    const u16* gB0 = Bsrc + (size_t)(n0 + ca * 16 + cr) * 1024 + cp * 8;
    const u16* gB1 = Bsrc + (size_t)(n0 + cb * 16 + cr) * 1024 + cp * 8;

    const int srow0 = tid >> 2, sq0 = tid & 3;     // A-staging row/quarter
    const int srow1 = srow0 + 64;

    float4 sv[2][2];

#define L2_LOAD(ktv) do{ \
    const float4* _p0 = reinterpret_cast<const float4*>( \
        Arow + (size_t)srow0 * astride + (ktv) * 32 + sq0 * 8); \
    const float4* _p1 = reinterpret_cast<const float4*>( \
        Arow + (size_t)srow1 * astride + (ktv) * 32 + sq0 * 8); \
    sv[0][0] = _p0[0]; sv[0][1] = _p0[1]; \
    sv[1][0] = _p1[0]; sv[1][1] = _p1[1]; }while(0)

#define L2_WRITE(bufv) do{ \
    _Pragma("unroll") \
    for (int rep = 0; rep < 2; rep++){ \
        const int row = (rep == 0) ? srow0 : srow1; \
        const float s = invc[row]; \
        float4 v0 = sv[rep][0], v1 = sv[rep][1]; \
        union { u16 h[8]; uint4 v; } pk; \
        pk.h[0] = f2bf(v0.x * s); pk.h[1] = f2bf(v0.y * s); \
        pk.h[2] = f2bf(v0.z * s); pk.h[3] = f2bf(v0.w * s); \
        pk.h[4] = f2bf(v1.x * s); pk.h[5] = f2bf(v1.y * s); \
        pk.h[6] = f2bf(v1.z * s); pk.h[7] = f2bf(v1.w * s); \
        *reinterpret_cast<uint4*>(&As[bufv][row * 32 + sq0 * 8]) = pk.v; \
    } }while(0)

    // prologue: stage kt=0 into buffer 0
    L2_LOAD(0);
    L2_WRITE(0);
    async16(gB0, &Bs[0][ca * 512]);
    async16(gB1, &Bs[0][cb * 512]);
    __syncthreads();

    f32x4 acc[4][4];
    #pragma unroll
    for (int a = 0; a < 4; a++)
        #pragma unroll
        for (int b = 0; b < 4; b++)
            #pragma unroll
            for (int e = 0; e < 4; e++) acc[a][b][e] = 0.f;

    int buf = 0;
    for (int kt = 0; kt < 32; ++kt){
        if (kt < 31) L2_LOAD(kt + 1);                     // global A, kt+1
        bf16x8 af[4], bg[4];
        #pragma unroll
        for (int mi = 0; mi < 4; mi++)
            af[mi] = *reinterpret_cast<const bf16x8*>(
                &As[buf][(wr * 64 + mi * 16 + t) * 32 + q * 8]);
        #pragma unroll
        for (int ni = 0; ni < 4; ni++)
            bg[ni] = *reinterpret_cast<const bf16x8*>(
                &Bs[buf][(wc * 64 + ni * 16 + t) * 32 + q * 8]);
        if (kt < 31){
            async16(gB0 + (kt + 1) * 32, &Bs[buf ^ 1][ca * 512]);
            async16(gB1 + (kt + 1) * 32, &Bs[buf ^ 1][cb * 512]);
        }
        __builtin_amdgcn_s_setprio(1);
        #pragma unroll
        for (int mi = 0; mi < 4; mi++)
            #pragma unroll
            for (int ni = 0; ni < 4; ni++)
                acc[mi][ni] = __builtin_amdgcn_mfma_f32_16x16x32_bf16(
                    af[mi], bg[ni], acc[mi][ni], 0, 0, 0);
        __builtin_amdgcn_s_setprio(0);
        if (kt < 31) L2_WRITE(buf ^ 1);                   // LDS A, kt+1
        __syncthreads();
        buf ^= 1;
    }
#undef L2_LOAD
#undef L2_WRITE

    const bool outbf = (flags[0] != 0);
    #pragma unroll
    for (int mi = 0; mi < 4; mi++){
        #pragma unroll
        for (int i = 0; i < 4; i++){
            int m_l = wr * 64 + mi * 16 + q * 4 + i;
            int node = node_of_slot[slotbase + m_l];
            bool ok = (node >= 0) && (z < 3 || labels[node] == k);
            if (!ok) continue;
            #pragma unroll
            for (int ni = 0; ni < 4; ni++){
                int n = n0 + wc * 64 + ni * 16 + t;
                float v = acc[mi][ni][i] + b2f[k * 1024 + n];
                size_t oi = (size_t)node * 1024 + n;
                if (outbf) ((u16*)dout)[oi] = f2bf(v);
                else       ((float*)dout)[oi] = v;
            }
        }
    }
}

// ---------------------------------------------------------------------------
extern "C" void kernel_launch(void* const* d_in, const int* in_sizes, int n_in,
                              void* d_out, int out_size, void* d_ws, size_t ws_size,
                              hipStream_t stream)
{
    constexpr int C = 256, R = 1024;
    constexpr int PPAD = 40064;          // 313 * 128
    constexpr int M1 = 3 * R;            // 3072 L1 rows (branch-major)
    constexpr int SLOTS = 512;           // 3*128 grouped + 128 overflow

    const void* x      = d_in[0];
    const void* masks  = d_in[1];
    const int*  labels = (const int*)d_in[2];
    (void)in_sizes; (void)n_in; (void)out_size; (void)ws_size;

    char* ws = (char*)d_ws;
    size_t off = 0;
    auto alloc = [&](size_t b)->size_t {
        size_t o = off; off += (b + 255) & ~(size_t)255; return o;
    };

    int*   flags   = (int*)  (ws + alloc(256));
    int*   nodemap = (int*)  (ws + alloc(512 * 4));
    int*   ovfflag = (int*)  (ws + alloc(256));
    u16*   feat    = (u16*)  (ws + alloc((size_t)PPAD * C * 2));    // [p][c]
    u16*   B1T     = (u16*)  (ws + alloc((size_t)M1 * C * 2));      // [m][c]
    float* b1f     = (float*)(ws + alloc((size_t)M1 * 4));
    float* b2f     = (float*)(ws + alloc((size_t)M1 * 4));
    u16*   mfT     = (u16*)  (ws + alloc((size_t)SLOTS * PPAD * 2));// [slot][p]
    // contiguous zero region: sums3 | sumsOvf | counts
    float* sums3   = (float*)(ws + alloc((size_t)384 * 1024 * 4));
    float* sumsOvf = (float*)(ws + alloc((size_t)128 * M1 * 4));
    float* counts  = (float*)(ws + alloc((size_t)SLOTS * 4));
    u16*   W2T     = (u16*)  (ws + alloc((size_t)3 * R * R * 2));

    // zero sums|sumsOvf|counts BEFORE mega_prep (trans blocks atomicAdd
    // counts inside mega_prep). mfT memset stays dropped (empty-slot rows
    // are garbage by design; node_of_slot gate in l2 discards them).
    hipMemsetAsync(sums3, 0,
        (size_t)384 * 1024 * 4 + (size_t)128 * M1 * 4 + (size_t)SLOTS * 4,
        stream);

    // ONE prep launch: probe + grouping + prep_combo + trans_mask_count
    constexpr int NPREP = 10016 + 768 + 3072 + 12;
    constexpr int NTRANS = 313 * 12;
    mega_prep<<<2 + NPREP + NTRANS, 256, 0, stream>>>(
        x, masks, labels,
        d_in[3], d_in[7], d_in[11],              // W1
        d_in[5], d_in[9], d_in[13],              // W2
        d_in[4], d_in[8], d_in[12],              // b1
        d_in[6], d_in[10], d_in[14],             // b2
        feat, B1T, W2T, b1f, b2f, mfT, counts,
        flags, nodemap, ovfflag);

    // fused L1 + mask-sum: 512 ids (8 idle), branch-per-XCD swizzle
    fused_l1_mask<0><<<512, 256, 0, stream>>>(
        B1T, feat, mfT, b1f, sums3, nullptr);
    // overflow path (skipped unless some label has > 128 nodes)
    fused_l1_mask<1><<<dim3(24, 8), 256, 0, stream>>>(
        B1T, feat, mfT, b1f, sumsOvf, ovfflag);

    // L2 + means + output gather, one launch
    l2_gemm<<<dim3(8, 1, 6), 256, 0, stream>>>(
        sums3, sumsOvf, counts, W2T, b2f, nodemap, labels, ovfflag,
        d_out, flags);
}

// Round 9
// 345.638 us; speedup vs baseline: 1.2596x; 1.0588x over previous
//
#include <hip/hip_runtime.h>

typedef unsigned short u16;
typedef unsigned int   u32;

using bf16x8 = __attribute__((ext_vector_type(8))) __bf16;
using f32x4  = __attribute__((ext_vector_type(4))) float;

__device__ __forceinline__ float bf2f(u16 h){ return __uint_as_float(((u32)h) << 16); }
__device__ __forceinline__ u16 f2bf(float f){
    u32 u = __float_as_uint(f);
    u32 r = u + 0x7FFFu + ((u >> 16) & 1u);   // round-to-nearest-even
    return (u16)(r >> 16);
}

// async global->LDS, 16B per lane; LDS dest = wave-uniform base + lane*16.
__device__ __forceinline__ void async16(const void* g, void* l){
    __builtin_amdgcn_global_load_lds(
        (const __attribute__((address_space(1))) unsigned int*)g,
        (__attribute__((address_space(3))) unsigned int*)l, 16, 0, 0);
}
__device__ __forceinline__ bf16x8 cvt8(uint4 v){
    union { uint4 u; bf16x8 b; } c; c.u = v; return c.b;
}

// ---------------------------------------------------------------------------
// Block 0: dtype probe. flags[0]=1 if floats bf16; flags[1]=mask dtype
// 0=u8,1=i32,2=bf16,3=f32.
// Block 1: label grouping. Blocks >= 2: grid-stride float4 zero of the
// sums|sumsOvf|counts region. (v13 form — proven R7.)
// ---------------------------------------------------------------------------
__global__ void probe_and_perm(const void* x, const void* masks, int* flags,
                               const int* labels, int* slot_of_node,
                               int* node_of_slot, int* ovf_flag,
                               float* zbuf, unsigned int zf4)
{
    if (blockIdx.x >= 2){
        const unsigned int nthr = (gridDim.x - 2) * blockDim.x;
        unsigned int i = (blockIdx.x - 2) * blockDim.x + threadIdx.x;
        float4 z = make_float4(0.f, 0.f, 0.f, 0.f);
        for (; i < zf4; i += nthr)
            reinterpret_cast<float4*>(zbuf)[i] = z;
        return;
    }
    if (blockIdx.x == 0){
        int l = threadIdx.x;
        if (l < 64){
            const u16* hx = (const u16*)x;
            int e0 = (hx[l] >> 7) & 0xFF;
            int e1 = (hx[l + 64] >> 7) & 0xFF;
            unsigned long long b0 = __ballot(e0 >= 100 && e0 <= 140);
            unsigned long long b1 = __ballot(e1 >= 100 && e1 <= 140);
            int cnt = __popcll(b0) + __popcll(b1);
            const u32* w  = (const u32*)masks;
            const u16* hm = (const u16*)masks;
            u32 v = w[l];
            unsigned long long i32bad = __ballot(v > 1u);
            unsigned long long f32bad = __ballot(v != 0u && v != 0x3F800000u);
            u16 h0 = hm[l], h1 = hm[l + 64];
            unsigned long long bfbad =
                __ballot((h0 != 0 && h0 != 0x3F80) || (h1 != 0 && h1 != 0x3F80));
            if (l == 0){
                flags[0] = (cnt >= 100) ? 1 : 0;
                int md = 0;
                if (!i32bad) md = 1; else if (!f32bad) md = 3; else if (!bfbad) md = 2;
                flags[1] = md;
            }
        }
        return;
    }
    __shared__ int lab[300];
    __shared__ unsigned char sp[300];
    int t = threadIdx.x;                      // 320 threads
    for (int idx = t; idx < 512; idx += 320) node_of_slot[idx] = -1;
    if (t < 300) lab[t] = labels[t];
    __syncthreads();
    int r = 0;
    if (t < 300){
        int k = lab[t];
        for (int j = 0; j < t; j++) r += (lab[j] == k);
        sp[t] = (r >= 128) ? 1 : 0;
    }
    __syncthreads();
    if (t < 300){
        int slot;
        if (!sp[t]) slot = lab[t] * 128 + r;
        else {
            int so = 0;
            for (int j = 0; j < t; j++) so += sp[j];
            slot = 384 + so;
        }
        slot_of_node[t] = slot;
        node_of_slot[slot] = t;
    }
    if (t == 0){
        int tot = 0;
        for (int j = 0; j < 300; j++) tot += sp[j];
        *ovf_flag = tot;
    }
}

// ---------------------------------------------------------------------------
// prep_combo v2: VECTORIZED 64x64-tile transposes.
// v14 post-mortem: tail is ~constant 228 us across fused versions; by
// elimination prep_combo (~85 MB at ~0.8 TB/s) is the whale — issue-bound:
// 4B scalar reads, 2B scalar writes (Common-mistake #2 on my own kernel).
// v2: per block one 64x64 tile: read float4 (fp32 src) / ushort4 (bf16 src)
// -> bf16 LDS tile [64][68] (2-lane/bank both phases) -> write uint4 (16B
// contiguous per lane). ~2x fewer mem instructions, 8x larger stores.
// Grid: feat 626x4=2504 (block pblk=625 writes the zero pad rows
// 40000..40063), B1T 3x64=192, W2T 3x256=768, bias 12.  Transpose math is
// identical to v1: d[j*ldd + i] = cvt(src[i*J + j]), zero when j >= J.
// ---------------------------------------------------------------------------
__global__ __launch_bounds__(256)
void prep_combo(const void* x,
    const void* w10, const void* w11, const void* w12,
    const void* w20, const void* w21, const void* w22,
    const void* bb10, const void* bb11, const void* bb12,
    const void* bb20, const void* bb21, const void* bb22,
    u16* feat, u16* B1T, u16* W2T, float* b1f, float* b2f, const int* flags)
{
    constexpr int NFEAT = 626 * 4;            // 2504
    constexpr int NB1 = NFEAT + 192;          // 2696
    constexpr int NW2 = NB1 + 768;            // 3464

    __shared__ u16 tile[64 * 68];             // 8704 B, pad 68 u16
    const int id = blockIdx.x;
    const bool isbf = (flags[0] != 0);
    const int tid = threadIdx.x;

    const void* src; u16* d; int J, ldd, i0, j0;
    if (id < NFEAT){
        int pblk = id >> 2, cblk = id & 3;
        src = x; d = feat; J = 40000; ldd = 256;
        j0 = pblk * 64; i0 = cblk * 64;
    } else if (id < NB1){
        int idx = id - NFEAT;
        int z = idx >> 6, r2 = idx & 63;
        src = (z == 0) ? w10 : (z == 1) ? w11 : w12;
        d = B1T + (size_t)z * 1024 * 256;
        J = 1024; ldd = 256;
        j0 = (r2 & 15) * 64; i0 = (r2 >> 4) * 64;
    } else if (id < NW2){
        int idx = id - NB1;
        int z = idx >> 8, r2 = idx & 255;
        src = (z == 0) ? w20 : (z == 1) ? w21 : w22;
        d = W2T + (size_t)z * 1024 * 1024;
        J = 1024; ldd = 1024;
        j0 = (r2 & 15) * 64; i0 = (r2 >> 4) * 64;
    } else {
        int idx = (id - NW2) * 256 + tid;
        if (idx < 3072){
            int k = idx >> 10, r2 = idx & 1023;
            const void* p1 = (k == 0) ? bb10 : (k == 1) ? bb11 : bb12;
            const void* p2 = (k == 0) ? bb20 : (k == 1) ? bb21 : bb22;
            b1f[idx] = isbf ? bf2f(((const u16*)p1)[r2]) : ((const float*)p1)[r2];
            b2f[idx] = isbf ? bf2f(((const u16*)p2)[r2]) : ((const float*)p2)[r2];
        }
        return;
    }

    const int wave = tid >> 6, lane = tid & 63;
    const int rr = wave * 4 + (lane >> 4);    // row within pass-group of 16
    const int cc = (lane & 15) * 4;           // col, 4-wide per lane

    // ---- read phase: src rows -> bf16 LDS tile (4 passes x 16 rows) ----
    if (j0 >= J){
        // fully out-of-range tile (feat zero-pad rows): zeros
        #pragma unroll
        for (int pass = 0; pass < 4; pass++){
            const int r = pass * 16 + rr;
            union { u16 h[4]; uint2 v; } pk;
            pk.h[0] = 0; pk.h[1] = 0; pk.h[2] = 0; pk.h[3] = 0;
            *reinterpret_cast<uint2*>(&tile[r * 68 + cc]) = pk.v;
        }
    } else if (isbf){
        const u16* sh = (const u16*)src;
        #pragma unroll
        for (int pass = 0; pass < 4; pass++){
            const int r = pass * 16 + rr;
            const size_t ix = (size_t)(i0 + r) * J + (j0 + cc);
            ushort4 v = *reinterpret_cast<const ushort4*>(&sh[ix]);
            union { u16 h[4]; uint2 u; } pk;
            pk.h[0] = v.x; pk.h[1] = v.y; pk.h[2] = v.z; pk.h[3] = v.w;
            *reinterpret_cast<uint2*>(&tile[r * 68 + cc]) = pk.u;
        }
    } else {
        const float* sf = (const float*)src;
        #pragma unroll
        for (int pass = 0; pass < 4; pass++){
            const int r = pass * 16 + rr;
            const size_t ix = (size_t)(i0 + r) * J + (j0 + cc);
            float4 v = *reinterpret_cast<const float4*>(&sf[ix]);
            union { u16 h[4]; uint2 u; } pk;
            pk.h[0] = f2bf(v.x); pk.h[1] = f2bf(v.y);
            pk.h[2] = f2bf(v.z); pk.h[3] = f2bf(v.w);
            *reinterpret_cast<uint2*>(&tile[r * 68 + cc]) = pk.u;
        }
    }
    __syncthreads();

    // ---- write phase: column gather -> 16B contiguous stores (2 passes) ----
    #pragma unroll
    for (int pass = 0; pass < 2; pass++){
        const int s = pass * 256 + tid;       // [0, 512)
        const int p = s & 63;                 // tile col = dest row offset
        const int chunk = s >> 6;             // [0, 8): 8 dest cols each
        union { u16 h[8]; uint4 v; } pk;
        #pragma unroll
        for (int k = 0; k < 8; k++)
            pk.h[k] = tile[(chunk * 8 + k) * 68 + p];
        *reinterpret_cast<uint4*>(
            &d[(size_t)(j0 + p) * ldd + i0 + chunk * 8]) = pk.v;
    }
}

// ---------------------------------------------------------------------------
// masks [P][NN] -> mfT[slot][p] bf16 {0,1} (rows permuted), fused popcount.
// (v12 form, restored verbatim — proven R5.) mfT NOT pre-zeroed: empty-slot
// rows carry garbage by design; node_of_slot gate in l2 discards them.
// ---------------------------------------------------------------------------
__global__ void trans_mask_count(const void* src, u16* dst,
                                 const int* slot_of_node, float* counts,
                                 const int* flags)
{
    constexpr int NN_ = 300, P_ = 40000, LDP = 40064;
    __shared__ u16 tile[128][33];    // [p_in][n_in]
    __shared__ int slt[32];
    const int p0 = blockIdx.x * 128, n0 = blockIdx.y * 32;
    const int tid = threadIdx.x;
    const int md = flags[1];
    if (tid < 32) slt[tid] = (n0 + tid < NN_) ? slot_of_node[n0 + tid] : -1;

    if (md == 0){
        const unsigned char* s8 = (const unsigned char*)src;
        const int tx = tid & 7, ty = tid >> 3;
        #pragma unroll
        for (int rep = 0; rep < 4; rep++){
            const int p = p0 + rep * 32 + ty;
            const int nb = n0 + tx * 4;
            u32 w = 0;
            if (p < P_){
                if (nb + 3 < NN_)
                    w = *(const u32*)(s8 + (size_t)p * NN_ + nb);
                else {
                    for (int b = 0; b < 4; b++)
                        if (nb + b < NN_)
                            w |= (u32)s8[(size_t)p * NN_ + nb + b] << (8 * b);
                }
            }
            #pragma unroll
            for (int b = 0; b < 4; b++)
                tile[rep * 32 + ty][tx * 4 + b] =
                    ((w >> (8 * b)) & 0xFFu) ? (u16)0x3F80 : (u16)0;
        }
    } else {
        #pragma unroll
        for (int it = 0; it < 16; it++){
            const int e = tid + it * 256;
            const int n_in = e & 31, p_in = e >> 5;
            const int p = p0 + p_in, n = n0 + n_in;
            u16 v = 0;
            if (p < P_ && n < NN_){
                size_t idx = (size_t)p * NN_ + n;
                bool on;
                if (md == 1)      on = ((const int*)src)[idx] != 0;
                else if (md == 2) on = ((const u16*)src)[idx] != 0;
                else              on = ((const float*)src)[idx] != 0.f;
                v = on ? (u16)0x3F80 : (u16)0;
            }
            tile[p_in][n_in] = v;
        }
    }
    __syncthreads();

    #pragma unroll
    for (int half = 0; half < 2; half++){
        const int row = tid >> 3;
        const int pos = (tid & 7) + half * 8;
        const int slot = slt[row];
        if (slot >= 0){
            union { u16 h[8]; uint4 v; } tmp;
            #pragma unroll
            for (int j = 0; j < 8; j++) tmp.h[j] = tile[pos * 8 + j][row];
            *reinterpret_cast<uint4*>(&dst[(size_t)slot * LDP + p0 + pos * 8]) = tmp.v;
        }
    }
    if (tid < 32){
        const int slot = slt[tid];
        if (slot >= 0){
            int c = 0;
            for (int p = 0; p < 128; p++) c += (tile[p][tid] != 0);
            if (c > 0) atomicAdd(&counts[slot], (float)c);
        }
    }
}

// ---------------------------------------------------------------------------
// FUSED L1 + mask-sum v12 (FROZEN — 122 us measured, best of v8..v14):
// 128-m tile, 64 KB As, 2 blocks/CU; Hs split along M; all-wave writes,
// 4 barriers/pt; masks loaded once at kt=6/7, reused by both halves.
// ---------------------------------------------------------------------------
template<int MAP>
__global__ __launch_bounds__(256, 2)
void fused_l1_mask(const u16* __restrict__ B1T, const u16* __restrict__ feat,
                   const u16* __restrict__ mfT, const float* __restrict__ b1f,
                   float* __restrict__ sums, const int* __restrict__ skipf)
{
    if constexpr (MAP == 1){ if (*skipf == 0) return; }
    constexpr int PPAD = 40064;
    __shared__ __align__(16) u16 As[32768];   // [8 kt][128 m][32 c]  64 KB
    __shared__ __align__(16) u16 Hs[8192];    // [4 pc][64 mh][32 p]  16 KB

    int bx, ts, te;
    if constexpr (MAP == 0){
        const int id = blockIdx.x;            // 512 ids, 8 idle
        const int r = id & 7, s = (id >> 3) & 7, g = id >> 6;
        const int combo = g * 8 + r;
        if (combo >= 63) return;
        const int branch = combo / 21, y = combo % 21;
        bx = branch * 8 + s;
        ts = y * 15; te = ts + 15; if (te > 313) te = 313;
    } else {
        bx = blockIdx.x;                      // [0,24) -> m over all 3072
        ts = blockIdx.y * 40; te = ts + 40; if (te > 313) te = 313;
        if (ts >= te) return;
    }
    const int m0 = bx * 128;
    const int srow = (MAP == 0) ? ((bx >> 3) * 128) : 384;

    const int tid = threadIdx.x;
    const int wave = tid >> 6, lane = tid & 63;
    const int t = lane & 15, q = lane >> 4;

    {
        const int cr = lane >> 2, cp = lane & 3;
        const int ca = wave * 2, cb = wave * 2 + 1;
        const u16* gA0 = B1T + (size_t)(m0 + ca * 16 + cr) * 256 + cp * 8;
        const u16* gA1 = B1T + (size_t)(m0 + cb * 16 + cr) * 256 + cp * 8;
        #pragma unroll
        for (int kt = 0; kt < 8; kt++){
            async16(gA0 + kt * 32, &As[kt * 4096 + ca * 512]);
            async16(gA1 + kt * 32, &As[kt * 4096 + cb * 512]);
        }
    }

    const u16* mrow = mfT + (size_t)(srow + wave * 32 + t) * PPAD + q * 8;
    const u16* gF   = feat + (size_t)(wave * 32 + t) * 256 + q * 8;
    const float4* bsrc = reinterpret_cast<const float4*>(b1f + m0) + q;

    f32x4 acc2[2][8];
    #pragma unroll
    for (int a = 0; a < 2; a++)
        #pragma unroll
        for (int b = 0; b < 8; b++)
            #pragma unroll
            for (int e = 0; e < 4; e++) acc2[a][b][e] = 0.f;

    uint4 bgv[2];
    #pragma unroll
    for (int ni = 0; ni < 2; ni++)
        bgv[ni] = *reinterpret_cast<const uint4*>(
            gF + (size_t)(ts * 128 + ni * 16) * 256);

    __syncthreads();   // As resident (+ bgv drained)

#define HWRITE(MOFF) do{                                                      \
    _Pragma("unroll")                                                         \
    for (int mi = 0; mi < 4; mi++){                                           \
        _Pragma("unroll")                                                     \
        for (int i = 0; i < 4; i++){                                          \
            const int m_l = mi * 16 + q * 4 + i;                              \
            _Pragma("unroll")                                                 \
            for (int ni = 0; ni < 2; ni++){                                   \
                const int pin = ni * 16 + t;                                  \
                float v = acc1[(MOFF) + mi][ni][i];                           \
                v = (v > 0.f) ? v : 0.f;                                      \
                const int cg = (pin >> 3) ^ q;                                \
                Hs[wave * 2048 + m_l * 32 + cg * 8 + (pin & 7)] = f2bf(v);    \
            }                                                                 \
        }                                                                     \
    }                                                                         \
}while(0)

#define S2HALF(NOFF) do{                                                      \
    _Pragma("unroll")                                                         \
    for (int lc = 0; lc < 4; lc++){                                           \
        const int hq_ = (q ^ ((t >> 2) & 3)) * 8;                             \
        bf16x8 hb0_ = *reinterpret_cast<const bf16x8*>(                       \
            &Hs[lc * 2048 + (0 * 16 + t) * 32 + hq_]);                        \
        bf16x8 hb1_ = *reinterpret_cast<const bf16x8*>(                       \
            &Hs[lc * 2048 + (1 * 16 + t) * 32 + hq_]);                        \
        bf16x8 hb2_ = *reinterpret_cast<const bf16x8*>(                       \
            &Hs[lc * 2048 + (2 * 16 + t) * 32 + hq_]);                        \
        bf16x8 hb3_ = *reinterpret_cast<const bf16x8*>(                       \
            &Hs[lc * 2048 + (3 * 16 + t) * 32 + hq_]);                        \
        __builtin_amdgcn_s_setprio(1);                                        \
        acc2[0][(NOFF)+0] = __builtin_amdgcn_mfma_f32_16x16x32_bf16(          \
            cvt8(mk[lc][0]), hb0_, acc2[0][(NOFF)+0], 0, 0, 0);               \
        acc2[0][(NOFF)+1] = __builtin_amdgcn_mfma_f32_16x16x32_bf16(          \
            cvt8(mk[lc][0]), hb1_, acc2[0][(NOFF)+1], 0, 0, 0);               \
        acc2[0][(NOFF)+2] = __builtin_amdgcn_mfma_f32_16x16x32_bf16(          \
            cvt8(mk[lc][0]), hb2_, acc2[0][(NOFF)+2], 0, 0, 0);               \
        acc2[0][(NOFF)+3] = __builtin_amdgcn_mfma_f32_16x16x32_bf16(          \
            cvt8(mk[lc][0]), hb3_, acc2[0][(NOFF)+3], 0, 0, 0);               \
        acc2[1][(NOFF)+0] = __builtin_amdgcn_mfma_f32_16x16x32_bf16(          \
            cvt8(mk[lc][1]), hb0_, acc2[1][(NOFF)+0], 0, 0, 0);               \
        acc2[1][(NOFF)+1] = __builtin_amdgcn_mfma_f32_16x16x32_bf16(          \
            cvt8(mk[lc][1]), hb1_, acc2[1][(NOFF)+1], 0, 0, 0);               \
        acc2[1][(NOFF)+2] = __builtin_amdgcn_mfma_f32_16x16x32_bf16(          \
            cvt8(mk[lc][1]), hb2_, acc2[1][(NOFF)+2], 0, 0, 0);               \
        acc2[1][(NOFF)+3] = __builtin_amdgcn_mfma_f32_16x16x32_bf16(          \
            cvt8(mk[lc][1]), hb3_, acc2[1][(NOFF)+3], 0, 0, 0);               \
        __builtin_amdgcn_s_setprio(0);                                        \
    }                                                                         \
}while(0)

    for (int pt = ts; pt < te; ++pt){
        const int p0 = pt * 128;

        f32x4 acc1[8][2];
        #pragma unroll
        for (int mi = 0; mi < 8; mi++){
            float4 bb = bsrc[mi * 4];
            #pragma unroll
            for (int ni = 0; ni < 2; ni++){
                acc1[mi][ni][0] = bb.x; acc1[mi][ni][1] = bb.y;
                acc1[mi][ni][2] = bb.z; acc1[mi][ni][3] = bb.w;
            }
        }

        uint4 mk[4][2];   // mask frags [lc][si], loaded once, used twice

        #pragma unroll
        for (int kt = 0; kt < 8; ++kt){
            bf16x8 af[8];
            #pragma unroll
            for (int mi = 0; mi < 8; mi++)
                af[mi] = *reinterpret_cast<const bf16x8*>(
                    &As[kt * 4096 + (mi * 16 + t) * 32 + q * 8]);
            uint4 nxt[2];
            if (kt < 7){
                #pragma unroll
                for (int ni = 0; ni < 2; ni++)
                    nxt[ni] = *reinterpret_cast<const uint4*>(
                        gF + (size_t)(p0 + ni * 16) * 256 + (kt + 1) * 32);
            }
            if (kt == 6){
                #pragma unroll
                for (int si = 0; si < 2; si++){
                    mk[0][si] = *reinterpret_cast<const uint4*>(
                        mrow + (size_t)(si * 16) * PPAD + p0 + 0 * 32);
                    mk[1][si] = *reinterpret_cast<const uint4*>(
                        mrow + (size_t)(si * 16) * PPAD + p0 + 1 * 32);
                }
            } else if (kt == 7){
                #pragma unroll
                for (int si = 0; si < 2; si++){
                    mk[2][si] = *reinterpret_cast<const uint4*>(
                        mrow + (size_t)(si * 16) * PPAD + p0 + 2 * 32);
                    mk[3][si] = *reinterpret_cast<const uint4*>(
                        mrow + (size_t)(si * 16) * PPAD + p0 + 3 * 32);
                }
            }
            __builtin_amdgcn_s_setprio(1);
            #pragma unroll
            for (int mi = 0; mi < 8; mi++)
                #pragma unroll
                for (int ni = 0; ni < 2; ni++)
                    acc1[mi][ni] = __builtin_amdgcn_mfma_f32_16x16x32_bf16(
                        af[mi], cvt8(bgv[ni]), acc1[mi][ni], 0, 0, 0);
            __builtin_amdgcn_s_setprio(0);
            if (kt < 7){ bgv[0] = nxt[0]; bgv[1] = nxt[1]; }
        }

        HWRITE(0);
        __syncthreads();   // Hs half-0 ready; mk drained (vmcnt 0)

        S2HALF(0);
        __syncthreads();   // protect Hs before half-1 writes

        HWRITE(4);
        if (pt + 1 < te){
            #pragma unroll
            for (int ni = 0; ni < 2; ni++)
                bgv[ni] = *reinterpret_cast<const uint4*>(
                    gF + (size_t)((pt + 1) * 128 + ni * 16) * 256);
        }
        __syncthreads();   // Hs half-1 ready

        S2HALF(4);
        __syncthreads();   // protect Hs before next p-tile's writes
    }
#undef HWRITE
#undef S2HALF

    #pragma unroll
    for (int si = 0; si < 2; si++){
        #pragma unroll
        for (int i = 0; i < 4; i++){
            const int slot_l = wave * 32 + si * 16 + q * 4 + i;
            #pragma unroll
            for (int ni = 0; ni < 8; ni++){
                const int m_l = ni * 16 + t;
                const float v = acc2[si][ni][i];
                if constexpr (MAP == 0)
                    atomicAdd(sums + (size_t)((bx >> 3) * 128 + slot_l) * 1024
                                   + (bx & 7) * 128 + m_l, v);
                else
                    atomicAdd(sums + (size_t)slot_l * 3072 + bx * 128 + m_l, v);
            }
        }
    }
}

// ---------------------------------------------------------------------------
// L2 GEMM (FROZEN): double-buffered, one barrier per K-step; A scaled by
// 1/count + bf16-converted during staging; epilogue bias + scatter.
// ---------------------------------------------------------------------------
__global__ __launch_bounds__(256)
void l2_gemm(const float* __restrict__ sums3, const float* __restrict__ sumsOvf,
             const float* __restrict__ counts, const u16* __restrict__ W2T,
             const float* __restrict__ b2f, const int* __restrict__ node_of_slot,
             const int* __restrict__ labels, const int* __restrict__ ovfflag,
             void* __restrict__ dout, const int* __restrict__ flags)
{
    const int z = blockIdx.z;
    const int k = (z >= 3) ? z - 3 : z;
    if (z >= 3 && *ovfflag == 0) return;
    const int n0 = blockIdx.x * 128;

    const float* Arow; int astride, slotbase;
    if (z < 3){ Arow = sums3 + (size_t)z * 128 * 1024; astride = 1024; slotbase = z * 128; }
    else      { Arow = sumsOvf + (size_t)k * 1024;     astride = 3072; slotbase = 384; }

    __shared__ __align__(16) u16 As[2][4096];
    __shared__ __align__(16) u16 Bs[2][4096];
    __shared__ float invc[128];

    const int tid  = threadIdx.x;
    const int wave = tid >> 6, lane = tid & 63;
    const int wr = wave >> 1, wc = wave & 1;
    const int t = lane & 15, q = lane >> 4;

    if (tid < 128){
        float c = counts[slotbase + tid];
        invc[tid] = (c > 0.f) ? 1.f / c : 0.f;
    }
    __syncthreads();

    const u16* Bsrc = W2T + (size_t)k * 1024 * 1024;
    const int cr = lane >> 2, cp = lane & 3;
    const int ca = wave * 2, cb = wave * 2 + 1;
    const u16* gB0 = Bsrc + (size_t)(n0 + ca * 16 + cr) * 1024 + cp * 8;
    const u16* gB1 = Bsrc + (size_t)(n0 + cb * 16 + cr) * 1024 + cp * 8;

    const int srow0 = tid >> 2, sq0 = tid & 3;     // A-staging row/quarter
    const int srow1 = srow0 + 64;

    float4 sv[2][2];

#define L2_LOAD(ktv) do{ \
    const float4* _p0 = reinterpret_cast<const float4*>( \
        Arow + (size_t)srow0 * astride + (ktv) * 32 + sq0 * 8); \
    const float4* _p1 = reinterpret_cast<const float4*>( \
        Arow + (size_t)srow1 * astride + (ktv) * 32 + sq0 * 8); \
    sv[0][0] = _p0[0]; sv[0][1] = _p0[1]; \
    sv[1][0] = _p1[0]; sv[1][1] = _p1[1]; }while(0)

#define L2_WRITE(bufv) do{ \
    _Pragma("unroll") \
    for (int rep = 0; rep < 2; rep++){ \
        const int row = (rep == 0) ? srow0 : srow1; \
        const float s = invc[row]; \
        float4 v0 = sv[rep][0], v1 = sv[rep][1]; \
        union { u16 h[8]; uint4 v; } pk; \
        pk.h[0] = f2bf(v0.x * s); pk.h[1] = f2bf(v0.y * s); \
        pk.h[2] = f2bf(v0.z * s); pk.h[3] = f2bf(v0.w * s); \
        pk.h[4] = f2bf(v1.x * s); pk.h[5] = f2bf(v1.y * s); \
        pk.h[6] = f2bf(v1.z * s); pk.h[7] = f2bf(v1.w * s); \
        *reinterpret_cast<uint4*>(&As[bufv][row * 32 + sq0 * 8]) = pk.v; \
    } }while(0)

    // prologue: stage kt=0 into buffer 0
    L2_LOAD(0);
    L2_WRITE(0);
    async16(gB0, &Bs[0][ca * 512]);
    async16(gB1, &Bs[0][cb * 512]);
    __syncthreads();

    f32x4 acc[4][4];
    #pragma unroll
    for (int a = 0; a < 4; a++)
        #pragma unroll
        for (int b = 0; b < 4; b++)
            #pragma unroll
            for (int e = 0; e < 4; e++) acc[a][b][e] = 0.f;

    int buf = 0;
    for (int kt = 0; kt < 32; ++kt){
        if (kt < 31) L2_LOAD(kt + 1);                     // global A, kt+1
        bf16x8 af[4], bg[4];
        #pragma unroll
        for (int mi = 0; mi < 4; mi++)
            af[mi] = *reinterpret_cast<const bf16x8*>(
                &As[buf][(wr * 64 + mi * 16 + t) * 32 + q * 8]);
        #pragma unroll
        for (int ni = 0; ni < 4; ni++)
            bg[ni] = *reinterpret_cast<const bf16x8*>(
                &Bs[buf][(wc * 64 + ni * 16 + t) * 32 + q * 8]);
        if (kt < 31){
            async16(gB0 + (kt + 1) * 32, &Bs[buf ^ 1][ca * 512]);
            async16(gB1 + (kt + 1) * 32, &Bs[buf ^ 1][cb * 512]);
        }
        __builtin_amdgcn_s_setprio(1);
        #pragma unroll
        for (int mi = 0; mi < 4; mi++)
            #pragma unroll
            for (int ni = 0; ni < 4; ni++)
                acc[mi][ni] = __builtin_amdgcn_mfma_f32_16x16x32_bf16(
                    af[mi], bg[ni], acc[mi][ni], 0, 0, 0);
        __builtin_amdgcn_s_setprio(0);
        if (kt < 31) L2_WRITE(buf ^ 1);                   // LDS A, kt+1
        __syncthreads();
        buf ^= 1;
    }
#undef L2_LOAD
#undef L2_WRITE

    const bool outbf = (flags[0] != 0);
    #pragma unroll
    for (int mi = 0; mi < 4; mi++){
        #pragma unroll
        for (int i = 0; i < 4; i++){
            int m_l = wr * 64 + mi * 16 + q * 4 + i;
            int node = node_of_slot[slotbase + m_l];
            bool ok = (node >= 0) && (z < 3 || labels[node] == k);
            if (!ok) continue;
            #pragma unroll
            for (int ni = 0; ni < 4; ni++){
                int n = n0 + wc * 64 + ni * 16 + t;
                float v = acc[mi][ni][i] + b2f[k * 1024 + n];
                size_t oi = (size_t)node * 1024 + n;
                if (outbf) ((u16*)dout)[oi] = f2bf(v);
                else       ((float*)dout)[oi] = v;
            }
        }
    }
}

// ---------------------------------------------------------------------------
extern "C" void kernel_launch(void* const* d_in, const int* in_sizes, int n_in,
                              void* d_out, int out_size, void* d_ws, size_t ws_size,
                              hipStream_t stream)
{
    constexpr int C = 256, R = 1024;
    constexpr int PPAD = 40064;          // 313 * 128
    constexpr int M1 = 3 * R;            // 3072 L1 rows (branch-major)
    constexpr int SLOTS = 512;           // 3*128 grouped + 128 overflow

    const void* x      = d_in[0];
    const void* masks  = d_in[1];
    const int*  labels = (const int*)d_in[2];
    (void)in_sizes; (void)n_in; (void)out_size; (void)ws_size;

    char* ws = (char*)d_ws;
    size_t off = 0;
    auto alloc = [&](size_t b)->size_t {
        size_t o = off; off += (b + 255) & ~(size_t)255; return o;
    };

    int*   flags   = (int*)  (ws + alloc(256));
    int*   slotmap = (int*)  (ws + alloc(384 * 4));
    int*   nodemap = (int*)  (ws + alloc(512 * 4));
    int*   ovfflag = (int*)  (ws + alloc(256));
    u16*   feat    = (u16*)  (ws + alloc((size_t)PPAD * C * 2));    // [p][c]
    u16*   B1T     = (u16*)  (ws + alloc((size_t)M1 * C * 2));      // [m][c]
    float* b1f     = (float*)(ws + alloc((size_t)M1 * 4));
    float* b2f     = (float*)(ws + alloc((size_t)M1 * 4));
    u16*   mfT     = (u16*)  (ws + alloc((size_t)SLOTS * PPAD * 2));// [slot][p]
    // contiguous zero region: sums3 | sumsOvf | counts
    float* sums3   = (float*)(ws + alloc((size_t)384 * 1024 * 4));
    float* sumsOvf = (float*)(ws + alloc((size_t)128 * M1 * 4));
    float* counts  = (float*)(ws + alloc((size_t)SLOTS * 4));
    u16*   W2T     = (u16*)  (ws + alloc((size_t)3 * R * R * 2));

    // sums|sumsOvf|counts zero region, in float4 units
    const unsigned int zf4 = (384u * 1024u + 128u * 3072u + 512u) / 4u;

    // probe + grouping + sums-memset in one launch (blocks >= 2 zero)
    probe_and_perm<<<66, 320, 0, stream>>>(x, masks, flags, labels,
                                           slotmap, nodemap, ovfflag,
                                           sums3, zf4);
    // NOTE: mfT memset dropped — empty-slot rows carry garbage by design.

    // vectorized 64x64-tile transposes: feat 2504 | B1T 192 | W2T 768 | bias 12
    prep_combo<<<2504 + 192 + 768 + 12, 256, 0, stream>>>(
        x, d_in[3], d_in[7], d_in[11],           // W1
        d_in[5], d_in[9], d_in[13],              // W2
        d_in[4], d_in[8], d_in[12],              // b1
        d_in[6], d_in[10], d_in[14],             // b2
        feat, B1T, W2T, b1f, b2f, flags);

    trans_mask_count<<<dim3(PPAD / 128, 384 / 32), 256, 0, stream>>>(
        masks, mfT, slotmap, counts, flags);

    // fused L1 + mask-sum: 512 ids (8 idle), branch-per-XCD swizzle
    fused_l1_mask<0><<<512, 256, 0, stream>>>(
        B1T, feat, mfT, b1f, sums3, nullptr);
    // overflow path (skipped unless some label has > 128 nodes)
    fused_l1_mask<1><<<dim3(24, 8), 256, 0, stream>>>(
        B1T, feat, mfT, b1f, sumsOvf, ovfflag);

    // L2 + means + output gather, one launch
    l2_gemm<<<dim3(8, 1, 6), 256, 0, stream>>>(
        sums3, sumsOvf, counts, W2T, b2f, nodemap, labels, ovfflag,
        d_out, flags);
}